// Round 8
// baseline (309.637 us; speedup 1.0000x reference)
//
#include <hip/hip_runtime.h>
#include <hip/hip_fp16.h>
#include <math.h>

#define IN_DIM   128
#define HEADS    2
#define OCOLS    128    // HEADS*OUT_DIM
#define NB_A     1024   // alpha_stats blocks (partition mapping depends on it)
#define BSHIFT   7      // 128 nodes per bucket
#define BNODES   128
#define MAXB     1024   // max buckets (N <= 131072)
#define PCOPIES  8      // split copies of bucket_cnt
#define CAP      2560   // sortgather LDS capacity (mean 2048 + ~11 sigma)
#define PARTB    128    // partition blocks = NB_A/8
#define SCALE    14.0f  // w' = 2^14 * w ; w<=1 always -> w' <= 16384 (fp16-safe)
#define LOG2E    1.4426950408889634f

typedef __attribute__((ext_vector_type(8))) _Float16 half8v;   // 16 B
typedef __attribute__((ext_vector_type(2))) _Float16 half2v;   // 4 B
typedef __attribute__((ext_vector_type(4))) float    floatx4;  // MFMA C/D

union h2u { half2v h; int i; };

// order-preserving float<->uint key for atomicMax over mixed-sign floats
__device__ inline unsigned fkey(float f) {
  unsigned u = __float_as_uint(f);
  return (u & 0x80000000u) ? ~u : (u | 0x80000000u);
}
__device__ inline float fdecode(unsigned k) {
  unsigned u = (k & 0x80000000u) ? (k & 0x7FFFFFFFu) : ~k;
  return __uint_as_float(u);
}

// ---- one-time: pack W into MFMA B-fragment order + zero counters/keys ----
__global__ __launch_bounds__(256) void pack_w_kernel(
    const float* __restrict__ W, half8v* __restrict__ wpack,
    int* __restrict__ bucket_cnt, unsigned* __restrict__ maxkeys) {
  int t = threadIdx.x;
  for (int i = t; i < PCOPIES * MAXB; i += 256) bucket_cnt[i] = 0;
  if (t < 4) maxkeys[t] = 0u;
  for (int s = t; s < 2048; s += 256) {
    int l = s & 63, ct = (s >> 6) & 7, kk = s >> 9;
    int q = l >> 4, n = l & 15;
    int c = ct * 16 + n;
    half8v f;
#pragma unroll
    for (int j = 0; j < 8; j++) {
      f[j] = (_Float16)W[(size_t)(kk * 32 + q * 8 + j) * OCOLS + c];
    }
    wpack[s] = f;
  }
}

// ------- MFMA GEMM + fused epilogue: h16, alr (log2-scaled), alr maxima ----
__global__ __launch_bounds__(256) void gemm_kernel(
    const float* __restrict__ x, const half8v* __restrict__ wpack,
    const float* __restrict__ attn_l, const float* __restrict__ attn_r,
    _Float16* __restrict__ h16, float* __restrict__ alr,
    unsigned* __restrict__ maxkeys, int N) {
  __shared__ half8v Wlds[2048];                          // 32 KB
  __shared__ __align__(16) _Float16 hstage[64 * OCOLS];  // 16 KB
  __shared__ float bm[4][4];
  const int tid = threadIdx.x;
  for (int i = tid; i < 2048; i += 256) Wlds[i] = wpack[i];

  const int wave = tid >> 6, lane = tid & 63;
  const int q = lane >> 4, m = lane & 15;
  const int rbase = blockIdx.x * 64 + wave * 16;
  const int arow = rbase + m;
  const bool rok = arow < N;

  half8v a[4];
#pragma unroll
  for (int kk = 0; kk < 4; kk++) {
    float4 u = rok ? *(const float4*)&x[(size_t)arow * IN_DIM + kk * 32 + q * 8]
                   : make_float4(0.f, 0.f, 0.f, 0.f);
    float4 v = rok ? *(const float4*)&x[(size_t)arow * IN_DIM + kk * 32 + q * 8 + 4]
                   : make_float4(0.f, 0.f, 0.f, 0.f);
    a[kk][0] = (_Float16)u.x; a[kk][1] = (_Float16)u.y;
    a[kk][2] = (_Float16)u.z; a[kk][3] = (_Float16)u.w;
    a[kk][4] = (_Float16)v.x; a[kk][5] = (_Float16)v.y;
    a[kk][6] = (_Float16)v.z; a[kk][7] = (_Float16)v.w;
  }
  __syncthreads();  // Wlds ready

  floatx4 acc[8];
#pragma unroll
  for (int ct = 0; ct < 8; ct++) {
    floatx4 c = {0.f, 0.f, 0.f, 0.f};
#pragma unroll
    for (int kk = 0; kk < 4; kk++) {
      c = __builtin_amdgcn_mfma_f32_16x16x32_f16(
          a[kk], Wlds[(kk * 8 + ct) * 64 + lane], c, 0, 0, 0);
    }
    acc[ct] = c;
  }

  float Al[8], Ar[8];
#pragma unroll
  for (int ct = 0; ct < 8; ct++) {
    Al[ct] = attn_l[ct * 16 + m];
    Ar[ct] = attn_r[ct * 16 + m];
  }
  float wm0 = -1e30f, wm1 = -1e30f, wm2 = -1e30f, wm3 = -1e30f;
#pragma unroll
  for (int r = 0; r < 4; r++) {
    float al0 = 0.f, al1 = 0.f, ar0 = 0.f, ar1 = 0.f;
#pragma unroll
    for (int ct = 0; ct < 4; ct++) {
      al0 += acc[ct][r] * Al[ct];
      ar0 += acc[ct][r] * Ar[ct];
      al1 += acc[ct + 4][r] * Al[ct + 4];
      ar1 += acc[ct + 4][r] * Ar[ct + 4];
    }
#pragma unroll
    for (int off = 1; off < 16; off <<= 1) {
      al0 += __shfl_xor(al0, off);
      al1 += __shfl_xor(al1, off);
      ar0 += __shfl_xor(ar0, off);
      ar1 += __shfl_xor(ar1, off);
    }
    wm0 = fmaxf(wm0, al0); wm1 = fmaxf(wm1, al1);
    wm2 = fmaxf(wm2, ar0); wm3 = fmaxf(wm3, ar1);
    int orow = rbase + q * 4 + r;
    if (m == 0 && orow < N) {
      *(float4*)&alr[(size_t)orow * 4] =
          make_float4(al0 * LOG2E, al1 * LOG2E, ar0 * LOG2E, ar1 * LOG2E);
    }
  }
  // wave max (quads hold distinct rows; within-quad identical)
  wm0 = fmaxf(wm0, __shfl_xor(wm0, 16)); wm0 = fmaxf(wm0, __shfl_xor(wm0, 32));
  wm1 = fmaxf(wm1, __shfl_xor(wm1, 16)); wm1 = fmaxf(wm1, __shfl_xor(wm1, 32));
  wm2 = fmaxf(wm2, __shfl_xor(wm2, 16)); wm2 = fmaxf(wm2, __shfl_xor(wm2, 32));
  wm3 = fmaxf(wm3, __shfl_xor(wm3, 16)); wm3 = fmaxf(wm3, __shfl_xor(wm3, 32));
  if (lane == 0) { bm[wave][0] = wm0; bm[wave][1] = wm1; bm[wave][2] = wm2; bm[wave][3] = wm3; }

  // stage C into LDS (fp16)
#pragma unroll
  for (int ct = 0; ct < 8; ct++) {
#pragma unroll
    for (int r = 0; r < 4; r++) {
      hstage[(wave * 16 + q * 4 + r) * OCOLS + ct * 16 + m] = (_Float16)acc[ct][r];
    }
  }
  __syncthreads();
  if (tid == 0) {
#pragma unroll
    for (int c = 0; c < 4; c++) {
      float mx = fmaxf(fmaxf(bm[0][c], bm[1][c]), fmaxf(bm[2][c], bm[3][c]));
      atomicMax(&maxkeys[c], fkey(mx * LOG2E));
    }
  }
  {
    int srow = tid >> 2, seg = tid & 3;
    int grow = blockIdx.x * 64 + srow;
    if (grow < N) {
      const int4* s = (const int4*)&hstage[srow * OCOLS + seg * 32];
      int4* d = (int4*)&h16[(size_t)grow * OCOLS + seg * 32];
      int4 v0 = s[0], v1 = s[1], v2 = s[2], v3 = s[3];
      d[0] = v0; d[1] = v1; d[2] = v2; d[3] = v3;
    }
  }
}

// ---- exp-sum partials (fixed M upper bound) + bucket hist (per-block) ----
__global__ __launch_bounds__(256) void alpha_stats_kernel(
    const int* __restrict__ src, const int* __restrict__ dst,
    const float* __restrict__ alr, const unsigned* __restrict__ maxkeys,
    float2* __restrict__ partials, int* __restrict__ bucket_cnt,
    int* __restrict__ blockhist, int E, int nb1) {
  __shared__ int hist[MAXB];
  for (int i = threadIdx.x; i < MAXB; i += 256) hist[i] = 0;
  __syncthreads();
  const float M0 = fmaxf(fdecode(maxkeys[0]) + fdecode(maxkeys[2]), 0.f);
  const float M1 = fmaxf(fdecode(maxkeys[1]) + fdecode(maxkeys[3]), 0.f);
  const char* ab = (const char*)alr;
  float s0 = 0.f, s1 = 0.f;
  for (int e = blockIdx.x * 256 + threadIdx.x; e < E; e += NB_A * 256) {
    int sn = src[e], dn = dst[e];
    atomicAdd(&hist[dn >> BSHIFT], 1);
    float2 as = *(const float2*)(ab + ((unsigned)sn << 4));      // al0, al1
    float2 ad = *(const float2*)(ab + ((unsigned)dn << 4) + 8);  // ar0, ar1
    float a0 = as.x + ad.x; a0 = fmaxf(a0, 0.2f * a0);
    float a1 = as.y + ad.y; a1 = fmaxf(a1, 0.2f * a1);
    s0 += __builtin_amdgcn_exp2f(a0 - M0);
    s1 += __builtin_amdgcn_exp2f(a1 - M1);
  }
  __syncthreads();
  for (int j = threadIdx.x; j < nb1; j += 256) {
    int h = hist[j];
    blockhist[(size_t)blockIdx.x * nb1 + j] = h;
    if (h) atomicAdd(&bucket_cnt[(blockIdx.x & (PCOPIES - 1)) * MAXB + j], h);
  }
#pragma unroll
  for (int off = 1; off < 64; off <<= 1) {
    s0 += __shfl_xor(s0, off);
    s1 += __shfl_xor(s1, off);
  }
  __shared__ float red[4][2];
  int wv = threadIdx.x >> 6, ln = threadIdx.x & 63;
  if (ln == 0) { red[wv][0] = s0; red[wv][1] = s1; }
  __syncthreads();
  if (threadIdx.x == 0) {
    partials[blockIdx.x] = make_float2(red[0][0] + red[1][0] + red[2][0] + red[3][0],
                                       red[0][1] + red[1][1] + red[2][1] + red[3][1]);
  }
}

// ---- bucket scan + stats finalize (one block) ----
__global__ __launch_bounds__(1024) void bucket_scan_kernel(
    const int* __restrict__ bucket_cnt, const float2* __restrict__ partials,
    const unsigned* __restrict__ maxkeys, int* __restrict__ bucket_off,
    int* __restrict__ bucket_cursor, float* __restrict__ stats, int nb1) {
  __shared__ int part[1024];
  int t = threadIdx.x;
  int v = 0;
  if (t < nb1) {
#pragma unroll
    for (int c = 0; c < PCOPIES; c++) v += bucket_cnt[c * MAXB + t];
  }
  part[t] = v;
  __syncthreads();
  for (int d = 1; d < 1024; d <<= 1) {
    int x = (t >= d) ? part[t - d] : 0;
    __syncthreads();
    part[t] += x;
    __syncthreads();
  }
  int excl = part[t] - v;
  if (t < nb1) { bucket_off[t] = excl; bucket_cursor[t] = excl; }
  if (t == 1023) bucket_off[nb1] = part[1023];  // == E
  // stats: S = sum of partials
  float2 p = partials[t];
  float s0 = p.x, s1 = p.y;
#pragma unroll
  for (int off = 1; off < 64; off <<= 1) {
    s0 += __shfl_xor(s0, off);
    s1 += __shfl_xor(s1, off);
  }
  __shared__ float red[16][2];
  int wv = t >> 6, ln = t & 63;
  if (ln == 0) { red[wv][0] = s0; red[wv][1] = s1; }
  __syncthreads();
  if (t == 0) {
    float S0 = 0.f, S1 = 0.f;
    for (int w = 0; w < 16; w++) { S0 += red[w][0]; S1 += red[w][1]; }
    float M0 = fmaxf(fdecode(maxkeys[0]) + fdecode(maxkeys[2]), 0.f);
    float M1 = fmaxf(fdecode(maxkeys[1]) + fdecode(maxkeys[3]), 0.f);
    stats[0] = M0 - SCALE; stats[1] = 1.f / S0;   // w' = 2^SCALE * w
    stats[2] = M1 - SCALE; stats[3] = 1.f / S1;
  }
}

// ---- partition: reserve via stored per-block hists, scatter packed pairs ---
__global__ __launch_bounds__(256) void partition_kernel(
    const int* __restrict__ src, const int* __restrict__ dst,
    const int* __restrict__ blockhist, int* __restrict__ bucket_cursor,
    unsigned* __restrict__ pairs, int E, int nb1) {
  __shared__ int cur[MAXB];
  const int t = threadIdx.x, p = blockIdx.x;
  for (int j = t; j < nb1; j += 256) {
    int s = 0;
#pragma unroll
    for (int k = 0; k < 8; k++) s += blockhist[(size_t)(8 * p + k) * nb1 + j];
    cur[j] = s ? atomicAdd(&bucket_cursor[j], s) : 0;
  }
  __syncthreads();
  for (int k = 0; k < 8; k++) {
    int b = 8 * p + k;  // same edge set as alpha_stats block b
    for (int e = b * 256 + t; e < E; e += NB_A * 256) {
      int sn = src[e], dn = dst[e];
      int slot = atomicAdd(&cur[dn >> BSHIFT], 1);
      pairs[slot] = (unsigned)sn | ((unsigned)(dn & (BNODES - 1)) << 17);
    }
  }
}

// ---- fused sort+gather: per-bucket LDS counting sort (weights computed
//      once per edge, fp16 x 2^14) then register-accumulated gather ----
__global__ __launch_bounds__(512) void sortgather_kernel(
    const unsigned* __restrict__ pairs, const int* __restrict__ bucket_off,
    const float* __restrict__ alr, const float* __restrict__ stats,
    const _Float16* __restrict__ h16, int2* __restrict__ gfall,
    float* __restrict__ out, int N, int nb1) {
  __shared__ unsigned pbuf[CAP];           // 10 KB
  __shared__ int2 buf[CAP];                // 20 KB  {src, w0w1 fp16x2}
  __shared__ float2 adsh[BNODES];          // 1 KB   {ar0, ar1}
  __shared__ int hist[BNODES], scanv[BNODES], nodeoff[BNODES + 1], cur[BNODES];
  const int b = blockIdx.x, t = threadIdx.x;
  const int base = b << BSHIFT;
  const int pbeg = bucket_off[b], pend = bucket_off[b + 1];
  const int cntE = pend - pbeg;
  const bool fits = (cntE <= CAP);

  if (t < BNODES) {
    hist[t] = 0;
    int node = base + t;
    if (node < N) {
      const float* ap = (const float*)((const char*)alr + ((unsigned)node << 4));
      adsh[t] = make_float2(ap[2], ap[3]);
    }
  }
  __syncthreads();
  // stage + histogram
  if (fits) {
    for (int i = t; i < cntE; i += 512) {
      unsigned pr = pairs[pbeg + i];
      pbuf[i] = pr;
      atomicAdd(&hist[pr >> 17], 1);
    }
  } else {
    for (int i = t; i < cntE; i += 512) atomicAdd(&hist[pairs[pbeg + i] >> 17], 1);
  }
  __syncthreads();
  // scan over 128 node counts
  if (t < BNODES) scanv[t] = hist[t];
  __syncthreads();
  for (int d = 1; d < BNODES; d <<= 1) {
    int x = (t >= d && t < BNODES) ? scanv[t - d] : 0;
    __syncthreads();
    if (t < BNODES) scanv[t] += x;
    __syncthreads();
  }
  if (t < BNODES) {
    int ex = scanv[t] - hist[t];
    nodeoff[t] = ex;
    cur[t] = ex;
  }
  if (t == 0) nodeoff[BNODES] = cntE;
  __syncthreads();
  // weights + counting-sort scatter (weight computed ONCE per edge)
  const float Madj0 = stats[0], invS0 = stats[1];
  const float Madj1 = stats[2], invS1 = stats[3];
  const char* ab = (const char*)alr;
  for (int i = t; i < cntE; i += 512) {
    unsigned pr = fits ? pbuf[i] : pairs[pbeg + i];
    int sn = (int)(pr & 0x1FFFFu);
    int d = (int)(pr >> 17);
    float2 as = *(const float2*)(ab + ((unsigned)sn << 4));
    float2 ad = adsh[d];
    float a0 = as.x + ad.x; a0 = fmaxf(a0, 0.2f * a0);
    float a1 = as.y + ad.y; a1 = fmaxf(a1, 0.2f * a1);
    float w0 = __builtin_amdgcn_exp2f(a0 - Madj0) * invS0;
    float w1 = __builtin_amdgcn_exp2f(a1 - Madj1) * invS1;
    h2u pk;
    pk.h = half2v{(_Float16)w0, (_Float16)w1};
    int slot = atomicAdd(&cur[d], 1);
    int2 ent = make_int2(sn, pk.i);
    if (fits) buf[slot] = ent;
    else gfall[pbeg + slot] = ent;
  }
  __syncthreads();
  // gather: 8 waves x 16 nodes each; 4 edge-slots x 16 column-lanes
  const int wv = t >> 6, ln = t & 63;
  const int sub = ln >> 4, l = ln & 15, head = l >> 3;
  const char* hb = (const char*)h16;
  const unsigned loff = (unsigned)l * 16u;
  for (int n = wv; n < BNODES; n += 8) {
    int beg = nodeoff[n], end = nodeoff[n + 1];
    float acc[8] = {0.f, 0.f, 0.f, 0.f, 0.f, 0.f, 0.f, 0.f};
    for (int i = beg + sub; i < end; i += 4) {
      int2 ent = fits ? buf[i] : gfall[pbeg + i];
      h2u pk; pk.i = ent.y;
      float w = (float)(head ? pk.h.y : pk.h.x);
      half8v hv = *(const half8v*)(hb + (((unsigned)ent.x << 8) + loff));
#pragma unroll
      for (int j = 0; j < 8; j++) acc[j] += w * (float)hv[j];
    }
#pragma unroll
    for (int j = 0; j < 8; j++) {
      acc[j] += __shfl_xor(acc[j], 16);
      acc[j] += __shfl_xor(acc[j], 32);
    }
    int node = base + n;
    if (sub == 0 && node < N) {
      const float ds = 0x1.0p-14f;  // undo 2^SCALE
      char* ob = (char*)out;
      unsigned obase = ((unsigned)node << 9) + (unsigned)l * 32u;
      *(float4*)(ob + obase)      = make_float4(acc[0] * ds, acc[1] * ds, acc[2] * ds, acc[3] * ds);
      *(float4*)(ob + obase + 16) = make_float4(acc[4] * ds, acc[5] * ds, acc[6] * ds, acc[7] * ds);
    }
  }
}

extern "C" void kernel_launch(void* const* d_in, const int* in_sizes, int n_in,
                              void* d_out, int out_size, void* d_ws, size_t ws_size,
                              hipStream_t stream) {
  const float* x      = (const float*)d_in[0];
  const int*   edge   = (const int*)d_in[1];   // [2, E]
  const float* W      = (const float*)d_in[2];
  const float* attn_l = (const float*)d_in[3];
  const float* attn_r = (const float*)d_in[4];

  const int N = in_sizes[0] / IN_DIM;
  const int E = in_sizes[1] / 2;
  const int* src = edge;
  const int* dst = edge + E;
  float* out = (float*)d_out;

  const int nb1 = (N + BNODES - 1) >> BSHIFT;  // 782 for N=100k (<= MAXB)

  // workspace layout (byte offsets, 16B-aligned regions)
  char* w = (char*)d_ws;
  size_t o = 0;
  _Float16* h16 = (_Float16*)(w + o);      o += (size_t)N * OCOLS * 2;   // 25.6 MB
  float*    alr = (float*)(w + o);         o += (size_t)N * 16;          // 1.6 MB
  float2*   partials = (float2*)(w + o);   o += (size_t)NB_A * 8;
  float*    stats = (float*)(w + o);       o += 16;
  unsigned* maxkeys = (unsigned*)(w + o);  o += 16;
  int*      bucket_cnt = (int*)(w + o);    o += (size_t)PCOPIES * MAXB * 4;
  int*      bucket_off = (int*)(w + o);    o += (size_t)(MAXB + 4) * 4;
  int*      bucket_cursor = (int*)(w + o); o += (size_t)MAXB * 4;
  int*      blockhist = (int*)(w + o);     o += (size_t)NB_A * nb1 * 4;
  o = (o + 15) & ~(size_t)15;
  unsigned* pairs = (unsigned*)(w + o);    o += (size_t)E * 4;
  int2*     gfall = (int2*)(w + o);        o += (size_t)E * 8;
  half8v*   wpack = (half8v*)(w + o);      // 32 KB

  pack_w_kernel<<<1, 256, 0, stream>>>(W, wpack, bucket_cnt, maxkeys);
  gemm_kernel<<<(N + 63) / 64, 256, 0, stream>>>(x, wpack, attn_l, attn_r,
                                                 h16, alr, maxkeys, N);
  alpha_stats_kernel<<<NB_A, 256, 0, stream>>>(src, dst, alr, maxkeys,
                                               partials, bucket_cnt, blockhist, E, nb1);
  bucket_scan_kernel<<<1, 1024, 0, stream>>>(bucket_cnt, partials, maxkeys,
                                             bucket_off, bucket_cursor, stats, nb1);
  partition_kernel<<<PARTB, 256, 0, stream>>>(src, dst, blockhist, bucket_cursor,
                                              pairs, E, nb1);
  sortgather_kernel<<<nb1, 512, 0, stream>>>(pairs, bucket_off, alr, stats,
                                             h16, gfall, out, N, nb1);
}